// Round 11
// baseline (761.883 us; speedup 1.0000x reference)
//
#include <hip/hip_runtime.h>
#include <cstdint>
#include <cstddef>

typedef __attribute__((ext_vector_type(4))) float f32x4;
typedef __attribute__((ext_vector_type(8))) short short8;

__device__ __forceinline__ float bf2f(unsigned short u) {
  union { unsigned int i; float f; } x; x.i = ((unsigned int)u) << 16; return x.f;
}
__device__ __forceinline__ unsigned short f2bf(float f) {
  union { float f; unsigned int i; } x; x.f = f;
  unsigned int r = x.i + 0x7fffu + ((x.i >> 16) & 1u);
  return (unsigned short)(r >> 16);
}
__device__ __forceinline__ void gload16(unsigned short* lds, const unsigned short* g) {
  __builtin_amdgcn_global_load_lds(
      (const __attribute__((address_space(1))) unsigned int*)g,
      (__attribute__((address_space(3))) unsigned int*)lds, 16, 0, 0);
}

// ---------------------------------------------------------------------------
// k_prep: all weight transforms + BN fold in one launch (block-range branch)
// ---------------------------------------------------------------------------
__global__ void k_prep(const float* __restrict__ w1, const float* __restrict__ w2,
                       const float* __restrict__ w3,
                       const float* __restrict__ g1, const float* __restrict__ b1,
                       const float* __restrict__ m1, const float* __restrict__ v1,
                       const float* __restrict__ g2, const float* __restrict__ b2,
                       const float* __restrict__ m2, const float* __restrict__ v2,
                       unsigned short* __restrict__ w1t, unsigned short* __restrict__ w2t,
                       unsigned short* __restrict__ w3b,
                       float* __restrict__ s1, float* __restrict__ bb1,
                       float* __restrict__ s2, float* __restrict__ bb2) {
  const int blk = blockIdx.x;
  const int tid = threadIdx.x;
  if (blk < 4608) {
    int i = blk * 256 + tid;
    int o = i / 4608, k = i - o * 4608;
    int cblk = k / 288, r = k - cblk * 288;
    int t = r >> 5, cl = r & 31;
    int ci = cblk * 32 + cl;
    int ty = t / 3, tx = t - ty * 3;
    w1t[i] = f2bf(w1[((o * 512 + ci) * 3 + ty) * 3 + tx]);
  } else if (blk < 5760) {
    int i = (blk - 4608) * 256 + tid;
    int o = i / 2304, k = i - o * 2304;
    int cblk = k / 288, r = k - cblk * 288;
    int t = r >> 5, cl = r & 31;
    int ci = cblk * 32 + cl;
    int ty = t / 3, tx = t - ty * 3;
    w2t[i] = f2bf(w2[((o * 256 + ci) * 3 + ty) * 3 + tx]);
  } else if (blk < 5776) {
    int i = (blk - 5760) * 256 + tid;
    int c = i >> 7, k = i & 127;
    w3b[i] = (c < 21) ? f2bf(w3[c * 128 + k]) : (unsigned short)0;
  } else {
    if (tid < 256) { float s = g1[tid] * rsqrtf(v1[tid] + 1e-5f); s1[tid] = s; bb1[tid] = b1[tid] - m1[tid] * s; }
    if (tid < 128) { float s = g2[tid] * rsqrtf(v2[tid] + 1e-5f); s2[tid] = s; bb2[tid] = b2[tid] - m2[tid] * s; }
  }
}

// ---------------------------------------------------------------------------
// k_labels_init: labels argmax [0,288) + fuP halo zero [288,1064) +
// objs zero [1064,1400)
// ---------------------------------------------------------------------------
__global__ void k_labels_init(const float* __restrict__ gp, signed char* __restrict__ lab,
                              unsigned short* __restrict__ fuP, float* __restrict__ objs) {
  const int blk = blockIdx.x;
  const int tid = threadIdx.x;
  if (blk < 288) {
    int p = blk * 256 + tid;
    int n = p / 9216, q = p - n * 9216;
    const float* g = gp + (long)n * 21 * 9216 + q;
    float best = g[0]; int bi = 0;
    #pragma unroll
    for (int c = 1; c < 21; c++) {
      float v = g[(long)c * 9216];
      if (v > best) { best = v; bi = c; }
    }
    lab[p] = (signed char)bi;
  } else if (blk < 1064) {
    int i = (blk - 288) * 256 + tid;
    const int B = 2 * 98 + 2 * 96;         // 388
    const int cg = i & 63; int b = i >> 6;
    const int n = b / B; b -= n * B;
    int y, x;
    if (b < 98) { y = 0; x = b; }
    else if (b < 196) { y = 97; x = b - 98; }
    else { int r = b - 196; y = 1 + (r >> 1); x = (r & 1) ? 97 : 0; }
    short8 z = {0, 0, 0, 0, 0, 0, 0, 0};
    *(short8*)&fuP[(((long)n * 98 + y) * 98 + x) * 512 + cg * 8] = z;
  } else {
    int i = (blk - 1064) * 256 + tid;
    objs[i] = 0.f;
  }
}

// em[p] = label if valid 5x5 window uniform, else -1
__global__ void k_em(const signed char* __restrict__ lab, signed char* __restrict__ em) {
  int p = blockIdx.x * 256 + threadIdx.x;
  int n = p / 9216, q = p - n * 9216, y = q / 96, x = q - y * 96;
  const signed char* L = lab + n * 9216;
  signed char l0 = L[q];
  bool uni = true;
  for (int dy = -2; dy <= 2; dy++) {
    int yy = y + dy; if (yy < 0 || yy > 95) continue;
    for (int dx = -2; dx <= 2; dx++) {
      int xx = x + dx; if (xx < 0 || xx > 95) continue;
      uni = uni && (L[yy * 96 + xx] == l0);
    }
  }
  em[p] = uni ? l0 : (signed char)-1;
}

// ---------------------------------------------------------------------------
// featT cast + objs accumulation fused
// ---------------------------------------------------------------------------
__global__ __launch_bounds__(256)
void k_featT_objs(const float* __restrict__ feat, const signed char* __restrict__ em,
                  unsigned short* __restrict__ featT, float* __restrict__ objs) {
  __shared__ float part[21 * 128];
  __shared__ int pres[21];
  const int g = blockIdx.x * 256 + threadIdx.x;
  const int n = g / 9216, p = g - n * 9216;
  const int fg0 = blockIdx.y * 16;
  const int tid = threadIdx.x;
  for (int i = tid; i < 21 * 128; i += 256) part[i] = 0.f;
  if (tid < 21) pres[tid] = 0;
  __syncthreads();
  const int c0 = em[g];
  if (c0 >= 0) pres[c0] = 1;
  const float* src = feat + (long)n * 512 * 9216 + p;
  unsigned short* dst = featT + ((long)n * 9216 + p) * 512;
  for (int fg = fg0; fg < fg0 + 16; fg++) {
    short8 o;
    float fv[8];
    #pragma unroll
    for (int j = 0; j < 8; j++) {
      fv[j] = src[(long)(fg * 8 + j) * 9216];
      o[j] = (short)f2bf(fv[j]);
    }
    *(short8*)&dst[fg * 8] = o;
    if (c0 >= 0) {
      const int lf0 = (fg - fg0) * 8;
      #pragma unroll
      for (int j = 0; j < 8; j++) atomicAdd(&part[c0 * 128 + lf0 + j], fv[j]);
    }
  }
  __syncthreads();
  for (int i = tid; i < 21 * 128; i += 256) {
    const int c = i >> 7, lf = i & 127;
    if (pres[c])
      atomicAdd(&objs[((long)n * 21 + c) * 512 + blockIdx.y * 128 + lf],
                part[i] * (1.0f / 9216.0f));
  }
}

// o2 + objs_c in one pass
__global__ void k_objfin(const float* __restrict__ objs, float* __restrict__ o2,
                         unsigned short* __restrict__ oc) {
  const int b = blockIdx.x;
  const int n = b >> 5, c = b & 31;
  const int lane = threadIdx.x;
  unsigned short* dst = oc + ((long)n * 32 + c) * 512;
  if (c < 21) {
    const float* o = objs + ((long)n * 21 + c) * 512;
    float s = 0.f;
    for (int f = lane; f < 512; f += 64) {
      float v = o[f];
      s += v * v;
      dst[f] = f2bf(v);
    }
    #pragma unroll
    for (int off = 32; off; off >>= 1) s += __shfl_down(s, off);
    if (lane == 0) o2[n * 21 + c] = s;
  } else {
    for (int f = lane; f < 512; f += 64) dst[f] = 0;
  }
}

// ---------------------------------------------------------------------------
// dist (MFMA) + fusion fused (verified R10 version)
// ---------------------------------------------------------------------------
__global__ __launch_bounds__(256)
void k_dist_fusion(const unsigned short* __restrict__ featT,
                   const unsigned short* __restrict__ objs_c,
                   const float* __restrict__ o2, const float* __restrict__ objs,
                   const signed char* __restrict__ em,
                   unsigned short* __restrict__ fuP) {
  __shared__ float ob[21 * 512];
  __shared__ float dl[64][21];
  __shared__ signed char eml[64];
  const int n = blockIdx.y;
  const int p0 = blockIdx.x * 64;
  const int tid = threadIdx.x;
  const int w = tid >> 6, lane = tid & 63;
  const int lrow = lane & 15, kg = lane >> 4;

  for (int i = tid; i < 21 * 512; i += 256) ob[i] = objs[(long)n * 21 * 512 + i];
  if (tid < 64) eml[tid] = em[n * 9216 + p0 + tid];

  const int px = p0 + w * 16 + lrow;
  const unsigned short* fb = featT + ((long)n * 9216 + px) * 512 + kg * 8;
  const unsigned short* a0p = objs_c + ((long)n * 32 + lrow) * 512 + kg * 8;
  const unsigned short* a1p = a0p + 16 * 512;
  f32x4 acc0 = {0.f, 0.f, 0.f, 0.f}, acc1 = {0.f, 0.f, 0.f, 0.f};
  float x2 = 0.f;
  #pragma unroll
  for (int s = 0; s < 16; s++) {
    const short8 b = *(const short8*)&fb[s * 32];
    const short8 a0 = *(const short8*)&a0p[s * 32];
    const short8 a1 = *(const short8*)&a1p[s * 32];
    acc0 = __builtin_amdgcn_mfma_f32_16x16x32_bf16(a0, b, acc0, 0, 0, 0);
    acc1 = __builtin_amdgcn_mfma_f32_16x16x32_bf16(a1, b, acc1, 0, 0, 0);
    #pragma unroll
    for (int j = 0; j < 8; j++) { float v = bf2f((unsigned short)b[j]); x2 += v * v; }
  }
  x2 += __shfl_xor(x2, 16); x2 += __shfl_xor(x2, 32);
  float cd[8], mx = -1e30f;
  #pragma unroll
  for (int r = 0; r < 4; r++) {
    const int c = kg * 4 + r;
    float d2 = x2 + o2[n * 21 + c] - 2.f * acc0[r];
    cd[r] = sqrtf(fmaxf(d2, 0.f)); mx = fmaxf(mx, cd[r]);
  }
  #pragma unroll
  for (int r = 0; r < 4; r++) {
    const int c = 16 + kg * 4 + r;
    if (c < 21) {
      float d2 = x2 + o2[n * 21 + c] - 2.f * acc1[r];
      cd[4 + r] = sqrtf(fmaxf(d2, 0.f)); mx = fmaxf(mx, cd[4 + r]);
    } else cd[4 + r] = -1e30f;
  }
  mx = fmaxf(mx, __shfl_xor(mx, 16)); mx = fmaxf(mx, __shfl_xor(mx, 32));
  float sum = 0.f;
  #pragma unroll
  for (int k = 0; k < 8; k++) {
    cd[k] = (cd[k] > -1e29f) ? __expf(cd[k] - mx) : 0.f;
    sum += cd[k];
  }
  sum += __shfl_xor(sum, 16); sum += __shfl_xor(sum, 32);
  const float inv = 1.f / sum;
  const int lpx = w * 16 + lrow;
  #pragma unroll
  for (int r = 0; r < 4; r++) dl[lpx][kg * 4 + r] = 1.f - cd[r] * inv;
  #pragma unroll
  for (int r = 0; r < 4; r++) {
    const int c = 16 + kg * 4 + r;
    if (c < 21) dl[lpx][c] = 1.f - cd[4 + r] * inv;
  }
  __syncthreads();

  const int px2 = tid & 63;
  const int fg = (tid >> 6) * 8;
  const int q = p0 + px2;
  const int y = q / 96, x = q - y * 96;
  unsigned short* dst = fuP + (((long)n * 98 + y + 1) * 98 + (x + 1)) * 512;
  const bool t = eml[px2] < 0;
  const unsigned short* srcT = featT + ((long)n * 9216 + q) * 512;
  for (int f0 = 0; f0 < 512; f0 += 32) {
    short8 o;
    const short8 fvv = *(const short8*)&srcT[f0 + fg];
    #pragma unroll
    for (int j = 0; j < 8; j++) {
      const int f = f0 + fg + j;
      float fv = bf2f((unsigned short)fvv[j]);
      if (t) {
        float of = 0.f;
        #pragma unroll
        for (int c = 0; c < 21; c++) of += dl[px2][c] * ob[c * 512 + f];
        fv = 0.1f * fv + 0.9f * of;
      }
      o[j] = (short)f2bf(fv);
    }
    *(short8*)&dst[fg] = o;
    dst += 32;
  }
}

// ---------------------------------------------------------------------------
// conv1: NEW 128x256 tile (BM=128 px, BN=256=COUT), BK=32, 4 waves as 1x4
// (each wave owns 128x64: 12 ds_read -> 32 MFMA, 375B LDS/MFMA vs 512 before
// — attacks the measured LDS-BW bound).  2-buffer (48KB), counted vmcnt(6),
// dual barrier: [vmcnt; barrier; kstep; barrier; stage(s+2)].
// ---------------------------------------------------------------------------
__global__ __launch_bounds__(256, 2)
void conv1_wide(const unsigned short* __restrict__ inP,
                const unsigned short* __restrict__ wT,
                const float* __restrict__ scale, const float* __restrict__ bias,
                unsigned short* __restrict__ out) {
  constexpr int CIN = 512, NK = 144;
  constexpr int Wout = 96, Hp = 98, Wp = 98;
  constexpr int HWo = 96 * 96;
  constexpr int KT = 9 * CIN;
  __shared__ unsigned short ldsA[2][4096];   // 128 rows x 32 ch
  __shared__ unsigned short ldsB[2][8192];   // 256 rows x 32 ch
  const int tid = threadIdx.x;
  const int chunk = gridDim.x >> 3;
  const int bid = (blockIdx.x & 7) * chunk + (blockIdx.x >> 3);
  const int bm0 = bid * 128;

  // staging: ids t+256k -> row = id>>2 (+64 per k), swizzled ch-slot invariant
  const int rA = tid >> 2;
  const int ch8 = (((tid & 3) ^ ((tid >> 3) & 3)) * 8);
  const int m0 = bm0 + rA, m1 = m0 + 64;
  const int n0 = m0 / HWo; const int q0 = m0 - n0 * HWo;
  const int y0 = q0 / Wout, x0 = q0 - y0 * Wout;
  const int n1 = m1 / HWo; const int q1 = m1 - n1 * HWo;
  const int y1 = q1 / Wout, x1 = q1 - y1 * Wout;
  const unsigned short* gA0 = inP + ((long)(n0 * Hp + y0) * Wp + x0) * CIN + ch8;
  const unsigned short* gA1 = inP + ((long)(n1 * Hp + y1) * Wp + x1) * CIN + ch8;
  const unsigned short* gB[4];
  #pragma unroll
  for (int k = 0; k < 4; k++) gB[k] = wT + (long)(rA + 64 * k) * KT + ch8;

  const int lane = tid & 63;
  const int wv = tid >> 6;               // wave col-block (1x4)
  const int lrow = lane & 15, kg = lane >> 4;
  const int aoff = lrow * 32 + ((kg ^ ((lrow >> 1) & 3)) * 8);       // + i*512
  const int brow0 = wv * 64 + lrow;
  const int boff = brow0 * 32 + ((kg ^ ((brow0 >> 1) & 3)) * 8);     // + j*512

  f32x4 acc[8][4];
  const f32x4 zero = {0.f, 0.f, 0.f, 0.f};
  #pragma unroll
  for (int i = 0; i < 8; i++)
    #pragma unroll
    for (int j = 0; j < 4; j++) acc[i][j] = zero;

  auto stage = [&](int b, int s) {
    const int cblk = s / 9;            // s = cblk*9 + t (tap-fastest)
    const int t = s - cblk * 9;
    const int ty = t / 3, tx = t - ty * 3;
    const long offA = (long)(ty * Wp + tx) * CIN + cblk * 32;
    gload16(&ldsA[b][tid * 8], gA0 + offA);
    gload16(&ldsA[b][2048 + tid * 8], gA1 + offA);
    const long k0 = (long)s * 32;
    #pragma unroll
    for (int k = 0; k < 4; k++)
      gload16(&ldsB[b][k * 2048 + tid * 8], gB[k] + k0);
  };

  auto kstep = [&](int rd) {
    const unsigned short* A = ldsA[rd];
    const unsigned short* B = ldsB[rd];
    short8 af[8], bfr[4];
    #pragma unroll
    for (int i = 0; i < 8; i++) af[i] = *(const short8*)&A[aoff + i * 512];
    #pragma unroll
    for (int j = 0; j < 4; j++) bfr[j] = *(const short8*)&B[boff + j * 512];
    __builtin_amdgcn_s_setprio(1);
    #pragma unroll
    for (int i = 0; i < 8; i++)
      #pragma unroll
      for (int j = 0; j < 4; j++)
        acc[i][j] = __builtin_amdgcn_mfma_f32_16x16x32_bf16(af[i], bfr[j], acc[i][j], 0, 0, 0);
    __builtin_amdgcn_s_setprio(0);
  };

  stage(0, 0);
  stage(1, 1);
  for (int s = 0; s < NK; ++s) {
    if (s < NK - 1)
      asm volatile("s_waitcnt vmcnt(6)" ::: "memory");   // stage(s) landed
    else
      asm volatile("s_waitcnt vmcnt(0)" ::: "memory");
    __builtin_amdgcn_s_barrier();                        // all waves' landed
    asm volatile("" ::: "memory");
    kstep(s & 1);
    __builtin_amdgcn_s_barrier();                        // reads of buf s&1 retired
    asm volatile("" ::: "memory");
    if (s + 2 < NK) stage(s & 1, s + 2);
  }

  #pragma unroll
  for (int i = 0; i < 8; i++) {
    const int row = bm0 + i * 16 + kg * 4;
    #pragma unroll
    for (int j = 0; j < 4; j++) {
      const int col = wv * 64 + j * 16 + lrow;
      const float sc = scale[col], bi = bias[col];
      #pragma unroll
      for (int r = 0; r < 4; r++) {
        float v = acc[i][j][r] * sc + bi;
        v = v > 0.f ? v : 0.f;
        out[(long)(row + r) * 256 + col] = f2bf(v);
      }
    }
  }
}

// ---------------------------------------------------------------------------
// conv2 + fused 1x1 conv3 + bias + softmax (R8 verbatim, passed three times)
// ---------------------------------------------------------------------------
__global__ __launch_bounds__(256)
void conv2_fused(const unsigned short* __restrict__ inP,
                 const unsigned short* __restrict__ wT,
                 const float* __restrict__ scale, const float* __restrict__ bias,
                 const unsigned short* __restrict__ w3b, const float* __restrict__ b3,
                 float* __restrict__ out) {
  constexpr int CIN = 256, NK = 72;
  constexpr int Wout = 192, Hp = 194, Wp = 194;
  constexpr int HWo = 192 * 192;
  constexpr int KT = 9 * CIN;
  __shared__ unsigned short pool[6 * 4096];
  const int tid = threadIdx.x;
  const int chunk = gridDim.x >> 3;
  const int bid = (blockIdx.x & 7) * chunk + (blockIdx.x >> 3);
  const int bm0 = bid * 128;

  const int rA = tid >> 2;
  const int ch8 = (((tid & 3) ^ ((tid >> 3) & 3)) * 8);
  const int m0 = bm0 + rA, m1 = m0 + 64;
  const int n0 = m0 / HWo; const int q0 = m0 - n0 * HWo;
  const int y0 = q0 / Wout, x0 = q0 - y0 * Wout;
  const int n1 = m1 / HWo; const int q1 = m1 - n1 * HWo;
  const int y1 = q1 / Wout, x1 = q1 - y1 * Wout;
  const unsigned short* gA0 = inP + ((long)(n0 * Hp + y0) * Wp + x0) * CIN + ch8;
  const unsigned short* gA1 = inP + ((long)(n1 * Hp + y1) * Wp + x1) * CIN + ch8;
  const unsigned short* gB0 = wT + (long)rA * KT + ch8;
  const unsigned short* gB1 = wT + (long)(rA + 64) * KT + ch8;

  const int lane = tid & 63;
  const int wv = tid >> 6;
  const int wr = wv >> 1, wc = wv & 1;
  const int lrow = lane & 15, kg = lane >> 4;
  const int arow = wr * 64 + lrow;
  const int aoff = arow * 32 + (kg ^ ((arow >> 1) & 3)) * 8;
  const int brow = wc * 64 + lrow;
  const int boff = brow * 32 + (kg ^ ((brow >> 1) & 3)) * 8;

  f32x4 acc[4][4];
  const f32x4 zero = {0.f, 0.f, 0.f, 0.f};
  #pragma unroll
  for (int i = 0; i < 4; i++)
    #pragma unroll
    for (int j = 0; j < 4; j++) acc[i][j] = zero;

  auto stage = [&](int b, int s) {
    const int cblk = s / 9;
    const int t = s - cblk * 9;
    const int ty = t / 3, tx = t - ty * 3;
    const long offA = (long)(ty * Wp + tx) * CIN + cblk * 32;
    gload16(&pool[b * 4096 + tid * 8], gA0 + offA);
    gload16(&pool[b * 4096 + 2048 + tid * 8], gA1 + offA);
    const long k0 = (long)s * 32;
    gload16(&pool[12288 + b * 4096 + tid * 8], gB0 + k0);
    gload16(&pool[12288 + b * 4096 + 2048 + tid * 8], gB1 + k0);
  };

  auto kstep = [&](int rd) {
    const unsigned short* A = &pool[rd * 4096];
    const unsigned short* B = &pool[12288 + rd * 4096];
    short8 af[4], bfr[4];
    #pragma unroll
    for (int i = 0; i < 4; i++) af[i] = *(const short8*)&A[aoff + i * 512];
    #pragma unroll
    for (int j = 0; j < 4; j++) bfr[j] = *(const short8*)&B[boff + j * 512];
    __builtin_amdgcn_s_setprio(1);
    #pragma unroll
    for (int i = 0; i < 4; i++)
      #pragma unroll
      for (int j = 0; j < 4; j++)
        acc[i][j] = __builtin_amdgcn_mfma_f32_16x16x32_bf16(af[i], bfr[j], acc[i][j], 0, 0, 0);
    __builtin_amdgcn_s_setprio(0);
  };

  stage(0, 0);
  stage(1, 1);
  int rd = 0;
  for (int s = 0; s < NK; ++s) {
    if (s < NK - 1)
      asm volatile("s_waitcnt vmcnt(4)" ::: "memory");
    else
      asm volatile("s_waitcnt vmcnt(0)" ::: "memory");
    __builtin_amdgcn_s_barrier();
    asm volatile("" ::: "memory");
    kstep(rd);
    if (s + 2 < NK) stage((rd + 2 >= 3) ? rd - 1 : rd + 2, s + 2);
    rd = (rd == 2) ? 0 : rd + 1;
  }

  asm volatile("s_waitcnt lgkmcnt(0)" ::: "memory");
  __builtin_amdgcn_s_barrier();
  asm volatile("" ::: "memory");
  #pragma unroll
  for (int j = 0; j < 4; j++) {
    const int ch = wc * 64 + j * 16 + lrow;
    const float sc = scale[ch], bi = bias[ch];
    #pragma unroll
    for (int i = 0; i < 4; i++) {
      const int pxb = wr * 64 + i * 16 + kg * 4;
      #pragma unroll
      for (int r = 0; r < 4; r++) {
        const int px = pxb + r;
        float v = acc[i][j][r] * sc + bi;
        v = v > 0.f ? v : 0.f;
        pool[px * 128 + (ch ^ ((px & 7) << 3))] = f2bf(v);
      }
    }
  }
  asm volatile("s_waitcnt lgkmcnt(0)" ::: "memory");
  __builtin_amdgcn_s_barrier();
  asm volatile("" ::: "memory");

  #pragma unroll
  for (int g = 0; g < 2; g++) {
    const int px = wv * 32 + g * 16 + lrow;
    f32x4 acc0 = {0.f, 0.f, 0.f, 0.f}, acc1 = {0.f, 0.f, 0.f, 0.f};
    #pragma unroll
    for (int s = 0; s < 4; s++) {
      const int ch0 = s * 32 + kg * 8;
      const short8 b = *(const short8*)&pool[px * 128 + (ch0 ^ ((px & 7) << 3))];
      const short8 a0 = *(const short8*)&w3b[lrow * 128 + ch0];
      const short8 a1 = *(const short8*)&w3b[(16 + lrow) * 128 + ch0];
      acc0 = __builtin_amdgcn_mfma_f32_16x16x32_bf16(a0, b, acc0, 0, 0, 0);
      acc1 = __builtin_amdgcn_mfma_f32_16x16x32_bf16(a1, b, acc1, 0, 0, 0);
    }
    float lg[8], mx = -1e30f;
    #pragma unroll
    for (int r = 0; r < 4; r++) {
      lg[r] = acc0[r] + b3[kg * 4 + r];
      mx = fmaxf(mx, lg[r]);
    }
    #pragma unroll
    for (int r = 0; r < 4; r++) {
      const int c = 16 + kg * 4 + r;
      if (c < 21) { lg[4 + r] = acc1[r] + b3[c]; mx = fmaxf(mx, lg[4 + r]); }
      else lg[4 + r] = -1e30f;
    }
    mx = fmaxf(mx, __shfl_xor(mx, 16)); mx = fmaxf(mx, __shfl_xor(mx, 32));
    float sum = 0.f;
    #pragma unroll
    for (int k = 0; k < 8; k++) {
      lg[k] = (lg[k] > -1e29f) ? __expf(lg[k] - mx) : 0.f;
      sum += lg[k];
    }
    sum += __shfl_xor(sum, 16); sum += __shfl_xor(sum, 32);
    const float inv = 1.f / sum;
    const int m = bm0 + px;
    const int n = m / HWo;
    const int q = m - n * HWo;
    #pragma unroll
    for (int r = 0; r < 4; r++)
      out[((long)n * 21 + kg * 4 + r) * (long)HWo + q] = lg[r] * inv;
    #pragma unroll
    for (int r = 0; r < 4; r++) {
      const int c = 16 + kg * 4 + r;
      if (c < 21) out[((long)n * 21 + c) * (long)HWo + q] = lg[4 + r] * inv;
    }
  }
}

// ---------------------------------------------------------------------------
// jax bilinear x2 -> padded h2P interior [0,36864) + halo zero [36864,+772)
// ---------------------------------------------------------------------------
__global__ void k_upsample(const unsigned short* __restrict__ h1,
                           unsigned short* __restrict__ h2P) {
  if (blockIdx.x >= 36864) {
    int i = (blockIdx.x - 36864) * 256 + threadIdx.x;
    const int B = 2 * 194 + 2 * 192;
    const int cg = i & 31; int b = i >> 5;
    const int n = b / B; b -= n * B;
    int y, x;
    if (b < 194) { y = 0; x = b; }
    else if (b < 388) { y = 193; x = b - 194; }
    else { int r = b - 388; y = 1 + (r >> 1); x = (r & 1) ? 193 : 0; }
    short8 z = {0, 0, 0, 0, 0, 0, 0, 0};
    *(short8*)&h2P[(((long)n * 194 + y) * 194 + x) * 256 + cg * 8] = z;
    return;
  }
  const int idx = blockIdx.x * 256 + threadIdx.x;
  const int c8 = (idx & 31) * 8;
  const int p = idx >> 5;
  const int n = p / 36864; const int rr = p - n * 36864;
  const int Y = rr / 192, X = rr - Y * 192;
  const int ky = Y >> 1, kx = X >> 1;
  int yA, yB, xA, xB; float wyA, wyB, wxA, wxB;
  if ((Y & 1) == 0) { yA = ky > 0 ? ky - 1 : 0; yB = ky; wyA = 0.25f; wyB = 0.75f; }
  else { yA = ky; yB = ky < 95 ? ky + 1 : 95; wyA = 0.75f; wyB = 0.25f; }
  if ((X & 1) == 0) { xA = kx > 0 ? kx - 1 : 0; xB = kx; wxA = 0.25f; wxB = 0.75f; }
  else { xA = kx; xB = kx < 95 ? kx + 1 : 95; wxA = 0.75f; wxB = 0.25f; }
  const unsigned short* hb = h1 + (long)n * 96 * 96 * 256 + c8;
  const short8 vaa = *(const short8*)&hb[((long)yA * 96 + xA) * 256];
  const short8 vab = *(const short8*)&hb[((long)yA * 96 + xB) * 256];
  const short8 vba = *(const short8*)&hb[((long)yB * 96 + xA) * 256];
  const short8 vbb = *(const short8*)&hb[((long)yB * 96 + xB) * 256];
  short8 o;
  #pragma unroll
  for (int j = 0; j < 8; j++) {
    float v = wyA * (wxA * bf2f((unsigned short)vaa[j]) + wxB * bf2f((unsigned short)vab[j])) +
              wyB * (wxA * bf2f((unsigned short)vba[j]) + wxB * bf2f((unsigned short)vbb[j]));
    o[j] = (short)f2bf(v);
  }
  *(short8*)&h2P[(((long)n * 194 + Y + 1) * 194 + X + 1) * 256 + c8] = o;
}

// ---------------------------------------------------------------------------
extern "C" void kernel_launch(void* const* d_in, const int* in_sizes, int n_in,
                              void* d_out, int out_size, void* d_ws, size_t ws_size,
                              hipStream_t stream) {
  const float* feature = (const float*)d_in[0];
  const float* gp = (const float*)d_in[1];
  const float* w1 = (const float*)d_in[2];
  const float* g1 = (const float*)d_in[3];
  const float* b1 = (const float*)d_in[4];
  const float* m1 = (const float*)d_in[5];
  const float* v1 = (const float*)d_in[6];
  const float* w2 = (const float*)d_in[7];
  const float* g2 = (const float*)d_in[8];
  const float* b2 = (const float*)d_in[9];
  const float* m2 = (const float*)d_in[10];
  const float* v2 = (const float*)d_in[11];
  const float* w3 = (const float*)d_in[12];
  const float* b3 = (const float*)d_in[13];
  float* out = (float*)d_out;

  char* ws = (char*)d_ws;
  size_t off = 0;
  auto alloc = [&](size_t bytes) -> void* {
    void* p = ws + off;
    off += (bytes + 255) & ~(size_t)255;
    return p;
  };
  signed char* lab = (signed char*)alloc(73728);
  signed char* em = (signed char*)alloc(73728);
  float* objs = (float*)alloc(8 * 21 * 512 * 4);
  float* o2 = (float*)alloc(168 * 4);
  unsigned short* objs_c = (unsigned short*)alloc((size_t)8 * 32 * 512 * 2);
  unsigned short* w1t = (unsigned short*)alloc((size_t)256 * 4608 * 2);
  unsigned short* w2t = (unsigned short*)alloc((size_t)128 * 2304 * 2);
  unsigned short* w3b = (unsigned short*)alloc((size_t)32 * 128 * 2);
  float* s1 = (float*)alloc(256 * 4);
  float* bb1 = (float*)alloc(256 * 4);
  float* s2 = (float*)alloc(128 * 4);
  float* bb2 = (float*)alloc(128 * 4);
  const size_t fuP_bytes = (size_t)8 * 98 * 98 * 512 * 2;    // 78.7 MB
  unsigned short* fuP = (unsigned short*)alloc(fuP_bytes);
  const size_t h1_bytes = (size_t)8 * 96 * 96 * 256 * 2;     // 37.7 MB
  unsigned short* h1 = (unsigned short*)alloc(h1_bytes);
  const size_t h2P_bytes = (size_t)8 * 194 * 194 * 256 * 2;  // 154.1 MB
  unsigned short* h2P = (unsigned short*)alloc(h2P_bytes);
  unsigned short* featT = h2P;   // featT (75.5 MB) dead before upsample fills h2P

  if (off > ws_size) return;  // workspace too small — fail loudly via wrong output

  k_prep<<<5777, 256, 0, stream>>>(w1, w2, w3, g1, b1, m1, v1, g2, b2, m2, v2,
                                   w1t, w2t, w3b, s1, bb1, s2, bb2);
  k_labels_init<<<1400, 256, 0, stream>>>(gp, lab, fuP, objs);
  k_em<<<288, 256, 0, stream>>>(lab, em);
  k_featT_objs<<<dim3(288, 4), 256, 0, stream>>>(feature, em, featT, objs);
  k_objfin<<<256, 64, 0, stream>>>(objs, o2, objs_c);
  k_dist_fusion<<<dim3(144, 8), 256, 0, stream>>>(featT, objs_c, o2, objs, em, fuP);

  conv1_wide<<<576, 256, 0, stream>>>(fuP, w1t, s1, bb1, h1);
  // featT (aliasing h2P) is dead from here on
  k_upsample<<<37636, 256, 0, stream>>>(h1, h2P);
  conv2_fused<<<2304, 256, 0, stream>>>(h2P, w2t, s2, bb2, w3b, b3, out);
}

// Round 12
// 720.172 us; speedup vs baseline: 1.0579x; 1.0579x over previous
//
#include <hip/hip_runtime.h>
#include <cstdint>
#include <cstddef>

typedef __attribute__((ext_vector_type(4))) float f32x4;
typedef __attribute__((ext_vector_type(8))) short short8;

__device__ __forceinline__ float bf2f(unsigned short u) {
  union { unsigned int i; float f; } x; x.i = ((unsigned int)u) << 16; return x.f;
}
__device__ __forceinline__ unsigned short f2bf(float f) {
  union { float f; unsigned int i; } x; x.f = f;
  unsigned int r = x.i + 0x7fffu + ((x.i >> 16) & 1u);
  return (unsigned short)(r >> 16);
}
__device__ __forceinline__ void gload16(unsigned short* lds, const unsigned short* g) {
  __builtin_amdgcn_global_load_lds(
      (const __attribute__((address_space(1))) unsigned int*)g,
      (__attribute__((address_space(3))) unsigned int*)lds, 16, 0, 0);
}

// ---------------------------------------------------------------------------
// k_prep: all weight transforms + BN fold in one launch (block-range branch)
// ---------------------------------------------------------------------------
__global__ void k_prep(const float* __restrict__ w1, const float* __restrict__ w2,
                       const float* __restrict__ w3,
                       const float* __restrict__ g1, const float* __restrict__ b1,
                       const float* __restrict__ m1, const float* __restrict__ v1,
                       const float* __restrict__ g2, const float* __restrict__ b2,
                       const float* __restrict__ m2, const float* __restrict__ v2,
                       unsigned short* __restrict__ w1t, unsigned short* __restrict__ w2t,
                       unsigned short* __restrict__ w3b,
                       float* __restrict__ s1, float* __restrict__ bb1,
                       float* __restrict__ s2, float* __restrict__ bb2) {
  const int blk = blockIdx.x;
  const int tid = threadIdx.x;
  if (blk < 4608) {
    int i = blk * 256 + tid;
    int o = i / 4608, k = i - o * 4608;
    int cblk = k / 288, r = k - cblk * 288;
    int t = r >> 5, cl = r & 31;
    int ci = cblk * 32 + cl;
    int ty = t / 3, tx = t - ty * 3;
    w1t[i] = f2bf(w1[((o * 512 + ci) * 3 + ty) * 3 + tx]);
  } else if (blk < 5760) {
    int i = (blk - 4608) * 256 + tid;
    int o = i / 2304, k = i - o * 2304;
    int cblk = k / 288, r = k - cblk * 288;
    int t = r >> 5, cl = r & 31;
    int ci = cblk * 32 + cl;
    int ty = t / 3, tx = t - ty * 3;
    w2t[i] = f2bf(w2[((o * 256 + ci) * 3 + ty) * 3 + tx]);
  } else if (blk < 5776) {
    int i = (blk - 5760) * 256 + tid;
    int c = i >> 7, k = i & 127;
    w3b[i] = (c < 21) ? f2bf(w3[c * 128 + k]) : (unsigned short)0;
  } else {
    if (tid < 256) { float s = g1[tid] * rsqrtf(v1[tid] + 1e-5f); s1[tid] = s; bb1[tid] = b1[tid] - m1[tid] * s; }
    if (tid < 128) { float s = g2[tid] * rsqrtf(v2[tid] + 1e-5f); s2[tid] = s; bb2[tid] = b2[tid] - m2[tid] * s; }
  }
}

// ---------------------------------------------------------------------------
// k_labels_init: labels argmax [0,288) + fuP halo zero [288,1064) +
// objs zero [1064,1400)
// ---------------------------------------------------------------------------
__global__ void k_labels_init(const float* __restrict__ gp, signed char* __restrict__ lab,
                              unsigned short* __restrict__ fuP, float* __restrict__ objs) {
  const int blk = blockIdx.x;
  const int tid = threadIdx.x;
  if (blk < 288) {
    int p = blk * 256 + tid;
    int n = p / 9216, q = p - n * 9216;
    const float* g = gp + (long)n * 21 * 9216 + q;
    float best = g[0]; int bi = 0;
    #pragma unroll
    for (int c = 1; c < 21; c++) {
      float v = g[(long)c * 9216];
      if (v > best) { best = v; bi = c; }
    }
    lab[p] = (signed char)bi;
  } else if (blk < 1064) {
    int i = (blk - 288) * 256 + tid;
    const int B = 2 * 98 + 2 * 96;         // 388
    const int cg = i & 63; int b = i >> 6;
    const int n = b / B; b -= n * B;
    int y, x;
    if (b < 98) { y = 0; x = b; }
    else if (b < 196) { y = 97; x = b - 98; }
    else { int r = b - 196; y = 1 + (r >> 1); x = (r & 1) ? 97 : 0; }
    short8 z = {0, 0, 0, 0, 0, 0, 0, 0};
    *(short8*)&fuP[(((long)n * 98 + y) * 98 + x) * 512 + cg * 8] = z;
  } else {
    int i = (blk - 1064) * 256 + tid;
    objs[i] = 0.f;
  }
}

// em[p] = label if valid 5x5 window uniform, else -1
__global__ void k_em(const signed char* __restrict__ lab, signed char* __restrict__ em) {
  int p = blockIdx.x * 256 + threadIdx.x;
  int n = p / 9216, q = p - n * 9216, y = q / 96, x = q - y * 96;
  const signed char* L = lab + n * 9216;
  signed char l0 = L[q];
  bool uni = true;
  for (int dy = -2; dy <= 2; dy++) {
    int yy = y + dy; if (yy < 0 || yy > 95) continue;
    for (int dx = -2; dx <= 2; dx++) {
      int xx = x + dx; if (xx < 0 || xx > 95) continue;
      uni = uni && (L[yy * 96 + xx] == l0);
    }
  }
  em[p] = uni ? l0 : (signed char)-1;
}

// ---------------------------------------------------------------------------
// featT cast + objs accumulation fused
// ---------------------------------------------------------------------------
__global__ __launch_bounds__(256)
void k_featT_objs(const float* __restrict__ feat, const signed char* __restrict__ em,
                  unsigned short* __restrict__ featT, float* __restrict__ objs) {
  __shared__ float part[21 * 128];
  __shared__ int pres[21];
  const int g = blockIdx.x * 256 + threadIdx.x;
  const int n = g / 9216, p = g - n * 9216;
  const int fg0 = blockIdx.y * 16;
  const int tid = threadIdx.x;
  for (int i = tid; i < 21 * 128; i += 256) part[i] = 0.f;
  if (tid < 21) pres[tid] = 0;
  __syncthreads();
  const int c0 = em[g];
  if (c0 >= 0) pres[c0] = 1;
  const float* src = feat + (long)n * 512 * 9216 + p;
  unsigned short* dst = featT + ((long)n * 9216 + p) * 512;
  for (int fg = fg0; fg < fg0 + 16; fg++) {
    short8 o;
    float fv[8];
    #pragma unroll
    for (int j = 0; j < 8; j++) {
      fv[j] = src[(long)(fg * 8 + j) * 9216];
      o[j] = (short)f2bf(fv[j]);
    }
    *(short8*)&dst[fg * 8] = o;
    if (c0 >= 0) {
      const int lf0 = (fg - fg0) * 8;
      #pragma unroll
      for (int j = 0; j < 8; j++) atomicAdd(&part[c0 * 128 + lf0 + j], fv[j]);
    }
  }
  __syncthreads();
  for (int i = tid; i < 21 * 128; i += 256) {
    const int c = i >> 7, lf = i & 127;
    if (pres[c])
      atomicAdd(&objs[((long)n * 21 + c) * 512 + blockIdx.y * 128 + lf],
                part[i] * (1.0f / 9216.0f));
  }
}

// o2 + objs_c in one pass
__global__ void k_objfin(const float* __restrict__ objs, float* __restrict__ o2,
                         unsigned short* __restrict__ oc) {
  const int b = blockIdx.x;
  const int n = b >> 5, c = b & 31;
  const int lane = threadIdx.x;
  unsigned short* dst = oc + ((long)n * 32 + c) * 512;
  if (c < 21) {
    const float* o = objs + ((long)n * 21 + c) * 512;
    float s = 0.f;
    for (int f = lane; f < 512; f += 64) {
      float v = o[f];
      s += v * v;
      dst[f] = f2bf(v);
    }
    #pragma unroll
    for (int off = 32; off; off >>= 1) s += __shfl_down(s, off);
    if (lane == 0) o2[n * 21 + c] = s;
  } else {
    for (int f = lane; f < 512; f += 64) dst[f] = 0;
  }
}

// ---------------------------------------------------------------------------
// dist (MFMA) + fusion fused (verified R10 version)
// ---------------------------------------------------------------------------
__global__ __launch_bounds__(256)
void k_dist_fusion(const unsigned short* __restrict__ featT,
                   const unsigned short* __restrict__ objs_c,
                   const float* __restrict__ o2, const float* __restrict__ objs,
                   const signed char* __restrict__ em,
                   unsigned short* __restrict__ fuP) {
  __shared__ float ob[21 * 512];
  __shared__ float dl[64][21];
  __shared__ signed char eml[64];
  const int n = blockIdx.y;
  const int p0 = blockIdx.x * 64;
  const int tid = threadIdx.x;
  const int w = tid >> 6, lane = tid & 63;
  const int lrow = lane & 15, kg = lane >> 4;

  for (int i = tid; i < 21 * 512; i += 256) ob[i] = objs[(long)n * 21 * 512 + i];
  if (tid < 64) eml[tid] = em[n * 9216 + p0 + tid];

  const int px = p0 + w * 16 + lrow;
  const unsigned short* fb = featT + ((long)n * 9216 + px) * 512 + kg * 8;
  const unsigned short* a0p = objs_c + ((long)n * 32 + lrow) * 512 + kg * 8;
  const unsigned short* a1p = a0p + 16 * 512;
  f32x4 acc0 = {0.f, 0.f, 0.f, 0.f}, acc1 = {0.f, 0.f, 0.f, 0.f};
  float x2 = 0.f;
  #pragma unroll
  for (int s = 0; s < 16; s++) {
    const short8 b = *(const short8*)&fb[s * 32];
    const short8 a0 = *(const short8*)&a0p[s * 32];
    const short8 a1 = *(const short8*)&a1p[s * 32];
    acc0 = __builtin_amdgcn_mfma_f32_16x16x32_bf16(a0, b, acc0, 0, 0, 0);
    acc1 = __builtin_amdgcn_mfma_f32_16x16x32_bf16(a1, b, acc1, 0, 0, 0);
    #pragma unroll
    for (int j = 0; j < 8; j++) { float v = bf2f((unsigned short)b[j]); x2 += v * v; }
  }
  x2 += __shfl_xor(x2, 16); x2 += __shfl_xor(x2, 32);
  float cd[8], mx = -1e30f;
  #pragma unroll
  for (int r = 0; r < 4; r++) {
    const int c = kg * 4 + r;
    float d2 = x2 + o2[n * 21 + c] - 2.f * acc0[r];
    cd[r] = sqrtf(fmaxf(d2, 0.f)); mx = fmaxf(mx, cd[r]);
  }
  #pragma unroll
  for (int r = 0; r < 4; r++) {
    const int c = 16 + kg * 4 + r;
    if (c < 21) {
      float d2 = x2 + o2[n * 21 + c] - 2.f * acc1[r];
      cd[4 + r] = sqrtf(fmaxf(d2, 0.f)); mx = fmaxf(mx, cd[4 + r]);
    } else cd[4 + r] = -1e30f;
  }
  mx = fmaxf(mx, __shfl_xor(mx, 16)); mx = fmaxf(mx, __shfl_xor(mx, 32));
  float sum = 0.f;
  #pragma unroll
  for (int k = 0; k < 8; k++) {
    cd[k] = (cd[k] > -1e29f) ? __expf(cd[k] - mx) : 0.f;
    sum += cd[k];
  }
  sum += __shfl_xor(sum, 16); sum += __shfl_xor(sum, 32);
  const float inv = 1.f / sum;
  const int lpx = w * 16 + lrow;
  #pragma unroll
  for (int r = 0; r < 4; r++) dl[lpx][kg * 4 + r] = 1.f - cd[r] * inv;
  #pragma unroll
  for (int r = 0; r < 4; r++) {
    const int c = 16 + kg * 4 + r;
    if (c < 21) dl[lpx][c] = 1.f - cd[4 + r] * inv;
  }
  __syncthreads();

  const int px2 = tid & 63;
  const int fg = (tid >> 6) * 8;
  const int q = p0 + px2;
  const int y = q / 96, x = q - y * 96;
  unsigned short* dst = fuP + (((long)n * 98 + y + 1) * 98 + (x + 1)) * 512;
  const bool t = eml[px2] < 0;
  const unsigned short* srcT = featT + ((long)n * 9216 + q) * 512;
  for (int f0 = 0; f0 < 512; f0 += 32) {
    short8 o;
    const short8 fvv = *(const short8*)&srcT[f0 + fg];
    #pragma unroll
    for (int j = 0; j < 8; j++) {
      const int f = f0 + fg + j;
      float fv = bf2f((unsigned short)fvv[j]);
      if (t) {
        float of = 0.f;
        #pragma unroll
        for (int c = 0; c < 21; c++) of += dl[px2][c] * ob[c * 512 + f];
        fv = 0.1f * fv + 0.9f * of;
      }
      o[j] = (short)f2bf(fv);
    }
    *(short8*)&dst[fg] = o;
    dst += 32;
  }
}

// ---------------------------------------------------------------------------
// conv1: implicit-GEMM 3x3, 128x128 tile, BK=32, 4 waves (R5 verbatim —
// measured best 253-257us across 7 dispatend runs).  3-buffer rotation,
// prefetch depth 2, dual s_barrier + counted vmcnt(8), tail peeled 4/0.
// ---------------------------------------------------------------------------
template <int CIN, int NK>
__global__ __launch_bounds__(256)
void conv3x3_gemm(const unsigned short* __restrict__ inP,
                  const unsigned short* __restrict__ wT,
                  const float* __restrict__ scale, const float* __restrict__ bias,
                  unsigned short* __restrict__ out,
                  int Hout, int Wout, int Hp, int Wp, int COUT, int nbN) {
  __shared__ unsigned short ldsA[3][4096];
  __shared__ unsigned short ldsB[3][4096];
  const int tid = threadIdx.x;
  const int chunk = gridDim.x >> 3;
  const int bid = (blockIdx.x & 7) * chunk + (blockIdx.x >> 3);
  const int mb = bid / nbN, nb = bid - mb * nbN;
  const int bm0 = mb * 128, bn0 = nb * 128;
  const int KT = 9 * CIN;
  const int HWo = Hout * Wout;

  const int rA = tid >> 2;
  const int ch8 = (((tid & 3) ^ ((tid >> 3) & 3)) * 8);
  const int m0 = bm0 + rA, m1 = m0 + 64;
  const int n0 = m0 / HWo; const int q0 = m0 - n0 * HWo;
  const int y0 = q0 / Wout, x0 = q0 - y0 * Wout;
  const int n1 = m1 / HWo; const int q1 = m1 - n1 * HWo;
  const int y1 = q1 / Wout, x1 = q1 - y1 * Wout;
  const unsigned short* gA0 = inP + ((long)(n0 * Hp + y0) * Wp + x0) * CIN + ch8;
  const unsigned short* gA1 = inP + ((long)(n1 * Hp + y1) * Wp + x1) * CIN + ch8;
  const unsigned short* gB0 = wT + (long)(bn0 + rA) * KT + ch8;
  const unsigned short* gB1 = wT + (long)(bn0 + rA + 64) * KT + ch8;

  const int lane = tid & 63;
  const int wv = tid >> 6;
  const int wr = wv >> 1, wc = wv & 1;
  const int lrow = lane & 15, kg = lane >> 4;
  const int arow = wr * 64 + lrow;
  const int aoff = arow * 32 + (kg ^ ((arow >> 1) & 3)) * 8;
  const int brow = wc * 64 + lrow;
  const int boff = brow * 32 + (kg ^ ((brow >> 1) & 3)) * 8;

  f32x4 acc[4][4];
  const f32x4 zero = {0.f, 0.f, 0.f, 0.f};
  #pragma unroll
  for (int i = 0; i < 4; i++)
    #pragma unroll
    for (int j = 0; j < 4; j++) acc[i][j] = zero;

  auto stage = [&](int b, int s) {
    const int cblk = s / 9;            // s = cblk*9 + t  (tap-fastest)
    const int t = s - cblk * 9;
    const int ty = t / 3, tx = t - ty * 3;
    const long offA = (long)(ty * Wp + tx) * CIN + cblk * 32;
    gload16(&ldsA[b][tid * 8], gA0 + offA);
    gload16(&ldsA[b][2048 + tid * 8], gA1 + offA);
    const long k0 = (long)s * 32;
    gload16(&ldsB[b][tid * 8], gB0 + k0);
    gload16(&ldsB[b][2048 + tid * 8], gB1 + k0);
  };

  auto kstep = [&](int rd) {
    const unsigned short* A = ldsA[rd];
    const unsigned short* B = ldsB[rd];
    short8 af[4], bfr[4];
    #pragma unroll
    for (int i = 0; i < 4; i++) af[i] = *(const short8*)&A[aoff + i * 512];
    #pragma unroll
    for (int j = 0; j < 4; j++) bfr[j] = *(const short8*)&B[boff + j * 512];
    __builtin_amdgcn_s_setprio(1);
    #pragma unroll
    for (int i = 0; i < 4; i++)
      #pragma unroll
      for (int j = 0; j < 4; j++)
        acc[i][j] = __builtin_amdgcn_mfma_f32_16x16x32_bf16(af[i], bfr[j], acc[i][j], 0, 0, 0);
    __builtin_amdgcn_s_setprio(0);
  };

  // prologue: 2 stages in flight
  stage(0, 0);
  stage(1, 1);
  int rd = 0, prev = 2;
  for (int s = 0; s < NK - 2; ++s) {
    __builtin_amdgcn_s_barrier();                    // barrier_A: buf[prev] free
    asm volatile("" ::: "memory");
    stage(prev, s + 2);
    asm volatile("s_waitcnt vmcnt(8)" ::: "memory"); // my buf[rd] loads landed
    __builtin_amdgcn_s_barrier();                    // barrier_B: all waves' landed
    asm volatile("" ::: "memory");
    kstep(rd);
    prev = rd; rd = (rd == 2) ? 0 : rd + 1;
  }
  // peel s = NK-2
  asm volatile("s_waitcnt vmcnt(4)" ::: "memory");
  __builtin_amdgcn_s_barrier();
  asm volatile("" ::: "memory");
  kstep(rd);
  rd = (rd == 2) ? 0 : rd + 1;
  // peel s = NK-1
  asm volatile("s_waitcnt vmcnt(0)" ::: "memory");
  __builtin_amdgcn_s_barrier();
  asm volatile("" ::: "memory");
  kstep(rd);

  #pragma unroll
  for (int i = 0; i < 4; i++) {
    const int row = bm0 + wr * 64 + i * 16 + kg * 4;
    #pragma unroll
    for (int j = 0; j < 4; j++) {
      const int col = bn0 + wc * 64 + j * 16 + lrow;
      const float sc = scale[col], bi = bias[col];
      #pragma unroll
      for (int r = 0; r < 4; r++) {
        float v = acc[i][j][r] * sc + bi;
        v = v > 0.f ? v : 0.f;
        out[(long)(row + r) * COUT + col] = f2bf(v);
      }
    }
  }
}

// ---------------------------------------------------------------------------
// conv2 + fused 1x1 conv3 + bias + softmax (R8 verbatim, passed four times)
// ---------------------------------------------------------------------------
__global__ __launch_bounds__(256)
void conv2_fused(const unsigned short* __restrict__ inP,
                 const unsigned short* __restrict__ wT,
                 const float* __restrict__ scale, const float* __restrict__ bias,
                 const unsigned short* __restrict__ w3b, const float* __restrict__ b3,
                 float* __restrict__ out) {
  constexpr int CIN = 256, NK = 72;
  constexpr int Wout = 192, Hp = 194, Wp = 194;
  constexpr int HWo = 192 * 192;
  constexpr int KT = 9 * CIN;
  __shared__ unsigned short pool[6 * 4096];
  const int tid = threadIdx.x;
  const int chunk = gridDim.x >> 3;
  const int bid = (blockIdx.x & 7) * chunk + (blockIdx.x >> 3);
  const int bm0 = bid * 128;

  const int rA = tid >> 2;
  const int ch8 = (((tid & 3) ^ ((tid >> 3) & 3)) * 8);
  const int m0 = bm0 + rA, m1 = m0 + 64;
  const int n0 = m0 / HWo; const int q0 = m0 - n0 * HWo;
  const int y0 = q0 / Wout, x0 = q0 - y0 * Wout;
  const int n1 = m1 / HWo; const int q1 = m1 - n1 * HWo;
  const int y1 = q1 / Wout, x1 = q1 - y1 * Wout;
  const unsigned short* gA0 = inP + ((long)(n0 * Hp + y0) * Wp + x0) * CIN + ch8;
  const unsigned short* gA1 = inP + ((long)(n1 * Hp + y1) * Wp + x1) * CIN + ch8;
  const unsigned short* gB0 = wT + (long)rA * KT + ch8;
  const unsigned short* gB1 = wT + (long)(rA + 64) * KT + ch8;

  const int lane = tid & 63;
  const int wv = tid >> 6;
  const int wr = wv >> 1, wc = wv & 1;
  const int lrow = lane & 15, kg = lane >> 4;
  const int arow = wr * 64 + lrow;
  const int aoff = arow * 32 + (kg ^ ((arow >> 1) & 3)) * 8;
  const int brow = wc * 64 + lrow;
  const int boff = brow * 32 + (kg ^ ((brow >> 1) & 3)) * 8;

  f32x4 acc[4][4];
  const f32x4 zero = {0.f, 0.f, 0.f, 0.f};
  #pragma unroll
  for (int i = 0; i < 4; i++)
    #pragma unroll
    for (int j = 0; j < 4; j++) acc[i][j] = zero;

  auto stage = [&](int b, int s) {
    const int cblk = s / 9;
    const int t = s - cblk * 9;
    const int ty = t / 3, tx = t - ty * 3;
    const long offA = (long)(ty * Wp + tx) * CIN + cblk * 32;
    gload16(&pool[b * 4096 + tid * 8], gA0 + offA);
    gload16(&pool[b * 4096 + 2048 + tid * 8], gA1 + offA);
    const long k0 = (long)s * 32;
    gload16(&pool[12288 + b * 4096 + tid * 8], gB0 + k0);
    gload16(&pool[12288 + b * 4096 + 2048 + tid * 8], gB1 + k0);
  };

  auto kstep = [&](int rd) {
    const unsigned short* A = &pool[rd * 4096];
    const unsigned short* B = &pool[12288 + rd * 4096];
    short8 af[4], bfr[4];
    #pragma unroll
    for (int i = 0; i < 4; i++) af[i] = *(const short8*)&A[aoff + i * 512];
    #pragma unroll
    for (int j = 0; j < 4; j++) bfr[j] = *(const short8*)&B[boff + j * 512];
    __builtin_amdgcn_s_setprio(1);
    #pragma unroll
    for (int i = 0; i < 4; i++)
      #pragma unroll
      for (int j = 0; j < 4; j++)
        acc[i][j] = __builtin_amdgcn_mfma_f32_16x16x32_bf16(af[i], bfr[j], acc[i][j], 0, 0, 0);
    __builtin_amdgcn_s_setprio(0);
  };

  stage(0, 0);
  stage(1, 1);
  int rd = 0;
  for (int s = 0; s < NK; ++s) {
    if (s < NK - 1)
      asm volatile("s_waitcnt vmcnt(4)" ::: "memory");
    else
      asm volatile("s_waitcnt vmcnt(0)" ::: "memory");
    __builtin_amdgcn_s_barrier();
    asm volatile("" ::: "memory");
    kstep(rd);
    if (s + 2 < NK) stage((rd + 2 >= 3) ? rd - 1 : rd + 2, s + 2);
    rd = (rd == 2) ? 0 : rd + 1;
  }

  asm volatile("s_waitcnt lgkmcnt(0)" ::: "memory");
  __builtin_amdgcn_s_barrier();
  asm volatile("" ::: "memory");
  #pragma unroll
  for (int j = 0; j < 4; j++) {
    const int ch = wc * 64 + j * 16 + lrow;
    const float sc = scale[ch], bi = bias[ch];
    #pragma unroll
    for (int i = 0; i < 4; i++) {
      const int pxb = wr * 64 + i * 16 + kg * 4;
      #pragma unroll
      for (int r = 0; r < 4; r++) {
        const int px = pxb + r;
        float v = acc[i][j][r] * sc + bi;
        v = v > 0.f ? v : 0.f;
        pool[px * 128 + (ch ^ ((px & 7) << 3))] = f2bf(v);
      }
    }
  }
  asm volatile("s_waitcnt lgkmcnt(0)" ::: "memory");
  __builtin_amdgcn_s_barrier();
  asm volatile("" ::: "memory");

  #pragma unroll
  for (int g = 0; g < 2; g++) {
    const int px = wv * 32 + g * 16 + lrow;
    f32x4 acc0 = {0.f, 0.f, 0.f, 0.f}, acc1 = {0.f, 0.f, 0.f, 0.f};
    #pragma unroll
    for (int s = 0; s < 4; s++) {
      const int ch0 = s * 32 + kg * 8;
      const short8 b = *(const short8*)&pool[px * 128 + (ch0 ^ ((px & 7) << 3))];
      const short8 a0 = *(const short8*)&w3b[lrow * 128 + ch0];
      const short8 a1 = *(const short8*)&w3b[(16 + lrow) * 128 + ch0];
      acc0 = __builtin_amdgcn_mfma_f32_16x16x32_bf16(a0, b, acc0, 0, 0, 0);
      acc1 = __builtin_amdgcn_mfma_f32_16x16x32_bf16(a1, b, acc1, 0, 0, 0);
    }
    float lg[8], mx = -1e30f;
    #pragma unroll
    for (int r = 0; r < 4; r++) {
      lg[r] = acc0[r] + b3[kg * 4 + r];
      mx = fmaxf(mx, lg[r]);
    }
    #pragma unroll
    for (int r = 0; r < 4; r++) {
      const int c = 16 + kg * 4 + r;
      if (c < 21) { lg[4 + r] = acc1[r] + b3[c]; mx = fmaxf(mx, lg[4 + r]); }
      else lg[4 + r] = -1e30f;
    }
    mx = fmaxf(mx, __shfl_xor(mx, 16)); mx = fmaxf(mx, __shfl_xor(mx, 32));
    float sum = 0.f;
    #pragma unroll
    for (int k = 0; k < 8; k++) {
      lg[k] = (lg[k] > -1e29f) ? __expf(lg[k] - mx) : 0.f;
      sum += lg[k];
    }
    sum += __shfl_xor(sum, 16); sum += __shfl_xor(sum, 32);
    const float inv = 1.f / sum;
    const int m = bm0 + px;
    const int n = m / HWo;
    const int q = m - n * HWo;
    #pragma unroll
    for (int r = 0; r < 4; r++)
      out[((long)n * 21 + kg * 4 + r) * (long)HWo + q] = lg[r] * inv;
    #pragma unroll
    for (int r = 0; r < 4; r++) {
      const int c = 16 + kg * 4 + r;
      if (c < 21) out[((long)n * 21 + c) * (long)HWo + q] = lg[4 + r] * inv;
    }
  }
}

// ---------------------------------------------------------------------------
// jax bilinear x2 -> padded h2P interior [0,36864) + halo zero [36864,+772)
// ---------------------------------------------------------------------------
__global__ void k_upsample(const unsigned short* __restrict__ h1,
                           unsigned short* __restrict__ h2P) {
  if (blockIdx.x >= 36864) {
    int i = (blockIdx.x - 36864) * 256 + threadIdx.x;
    const int B = 2 * 194 + 2 * 192;
    const int cg = i & 31; int b = i >> 5;
    const int n = b / B; b -= n * B;
    int y, x;
    if (b < 194) { y = 0; x = b; }
    else if (b < 388) { y = 193; x = b - 194; }
    else { int r = b - 388; y = 1 + (r >> 1); x = (r & 1) ? 193 : 0; }
    short8 z = {0, 0, 0, 0, 0, 0, 0, 0};
    *(short8*)&h2P[(((long)n * 194 + y) * 194 + x) * 256 + cg * 8] = z;
    return;
  }
  const int idx = blockIdx.x * 256 + threadIdx.x;
  const int c8 = (idx & 31) * 8;
  const int p = idx >> 5;
  const int n = p / 36864; const int rr = p - n * 36864;
  const int Y = rr / 192, X = rr - Y * 192;
  const int ky = Y >> 1, kx = X >> 1;
  int yA, yB, xA, xB; float wyA, wyB, wxA, wxB;
  if ((Y & 1) == 0) { yA = ky > 0 ? ky - 1 : 0; yB = ky; wyA = 0.25f; wyB = 0.75f; }
  else { yA = ky; yB = ky < 95 ? ky + 1 : 95; wyA = 0.75f; wyB = 0.25f; }
  if ((X & 1) == 0) { xA = kx > 0 ? kx - 1 : 0; xB = kx; wxA = 0.25f; wxB = 0.75f; }
  else { xA = kx; xB = kx < 95 ? kx + 1 : 95; wxA = 0.75f; wxB = 0.25f; }
  const unsigned short* hb = h1 + (long)n * 96 * 96 * 256 + c8;
  const short8 vaa = *(const short8*)&hb[((long)yA * 96 + xA) * 256];
  const short8 vab = *(const short8*)&hb[((long)yA * 96 + xB) * 256];
  const short8 vba = *(const short8*)&hb[((long)yB * 96 + xA) * 256];
  const short8 vbb = *(const short8*)&hb[((long)yB * 96 + xB) * 256];
  short8 o;
  #pragma unroll
  for (int j = 0; j < 8; j++) {
    float v = wyA * (wxA * bf2f((unsigned short)vaa[j]) + wxB * bf2f((unsigned short)vab[j])) +
              wyB * (wxA * bf2f((unsigned short)vba[j]) + wxB * bf2f((unsigned short)vbb[j]));
    o[j] = (short)f2bf(v);
  }
  *(short8*)&h2P[(((long)n * 194 + Y + 1) * 194 + X + 1) * 256 + c8] = o;
}

// ---------------------------------------------------------------------------
extern "C" void kernel_launch(void* const* d_in, const int* in_sizes, int n_in,
                              void* d_out, int out_size, void* d_ws, size_t ws_size,
                              hipStream_t stream) {
  const float* feature = (const float*)d_in[0];
  const float* gp = (const float*)d_in[1];
  const float* w1 = (const float*)d_in[2];
  const float* g1 = (const float*)d_in[3];
  const float* b1 = (const float*)d_in[4];
  const float* m1 = (const float*)d_in[5];
  const float* v1 = (const float*)d_in[6];
  const float* w2 = (const float*)d_in[7];
  const float* g2 = (const float*)d_in[8];
  const float* b2 = (const float*)d_in[9];
  const float* m2 = (const float*)d_in[10];
  const float* v2 = (const float*)d_in[11];
  const float* w3 = (const float*)d_in[12];
  const float* b3 = (const float*)d_in[13];
  float* out = (float*)d_out;

  char* ws = (char*)d_ws;
  size_t off = 0;
  auto alloc = [&](size_t bytes) -> void* {
    void* p = ws + off;
    off += (bytes + 255) & ~(size_t)255;
    return p;
  };
  signed char* lab = (signed char*)alloc(73728);
  signed char* em = (signed char*)alloc(73728);
  float* objs = (float*)alloc(8 * 21 * 512 * 4);
  float* o2 = (float*)alloc(168 * 4);
  unsigned short* objs_c = (unsigned short*)alloc((size_t)8 * 32 * 512 * 2);
  unsigned short* w1t = (unsigned short*)alloc((size_t)256 * 4608 * 2);
  unsigned short* w2t = (unsigned short*)alloc((size_t)128 * 2304 * 2);
  unsigned short* w3b = (unsigned short*)alloc((size_t)32 * 128 * 2);
  float* s1 = (float*)alloc(256 * 4);
  float* bb1 = (float*)alloc(256 * 4);
  float* s2 = (float*)alloc(128 * 4);
  float* bb2 = (float*)alloc(128 * 4);
  const size_t fuP_bytes = (size_t)8 * 98 * 98 * 512 * 2;    // 78.7 MB
  unsigned short* fuP = (unsigned short*)alloc(fuP_bytes);
  const size_t h1_bytes = (size_t)8 * 96 * 96 * 256 * 2;     // 37.7 MB
  unsigned short* h1 = (unsigned short*)alloc(h1_bytes);
  const size_t h2P_bytes = (size_t)8 * 194 * 194 * 256 * 2;  // 154.1 MB
  unsigned short* h2P = (unsigned short*)alloc(h2P_bytes);
  unsigned short* featT = h2P;   // featT (75.5 MB) dead before upsample fills h2P

  if (off > ws_size) return;  // workspace too small — fail loudly via wrong output

  k_prep<<<5777, 256, 0, stream>>>(w1, w2, w3, g1, b1, m1, v1, g2, b2, m2, v2,
                                   w1t, w2t, w3b, s1, bb1, s2, bb2);
  k_labels_init<<<1400, 256, 0, stream>>>(gp, lab, fuP, objs);
  k_em<<<288, 256, 0, stream>>>(lab, em);
  k_featT_objs<<<dim3(288, 4), 256, 0, stream>>>(feature, em, featT, objs);
  k_objfin<<<256, 64, 0, stream>>>(objs, o2, objs_c);
  k_dist_fusion<<<dim3(144, 8), 256, 0, stream>>>(featT, objs_c, o2, objs, em, fuP);

  conv3x3_gemm<512, 144><<<1152, 256, 0, stream>>>(fuP, w1t, s1, bb1, h1,
                                                   96, 96, 98, 98, 256, 2);
  // featT (aliasing h2P) is dead from here on
  k_upsample<<<37636, 256, 0, stream>>>(h1, h2P);
  conv2_fused<<<2304, 256, 0, stream>>>(h2P, w2t, s2, bb2, w3b, b3, out);
}